// Round 7
// baseline (8657.046 us; speedup 1.0000x reference)
//
#include <hip/hip_runtime.h>
#include <hip/hip_fp16.h>
#include <math.h>

// Problem constants (fixed by the reference)
#define NNODE   100000
#define NEDGE   3200000
#define NFEAT   512
#define NH      256
#define NC      40
#define NL      8

#define SCAN_B  256
#define NB      25        // col buckets: b = col >> 12 (4096 cols = 2MB h16 per bucket)
#define RPW     25        // rows per wave (persistent spmm)
#define RPB     100       // rows per block = 4 waves * RPW
#define PBLK    1024      // persistent blocks (4096 waves, all resident at 16 waves/CU)

typedef _Float16 f16x8 __attribute__((ext_vector_type(8)));
typedef float    f32x4 __attribute__((ext_vector_type(4)));

#define VAL_SCALE 9.5367431640625e-7f   // 2^-20

// ---------------------------------------------------------------------------
// CSR2 build: per-(row,bucket) count -> row scan -> per-row prefix -> scatter
// ---------------------------------------------------------------------------
__global__ void cnt2_kernel(const int* __restrict__ rows, const int* __restrict__ cols,
                            int* __restrict__ cnt2, int e) {
    int i = blockIdx.x * blockDim.x + threadIdx.x;
    if (i < e) atomicAdd(&cnt2[rows[i] * NB + (cols[i] >> 12)], 1);
}

// scan pass 1: per-row degree = sum of its NB bucket counts, block-local scan
__global__ void scan_pass1(const int* __restrict__ cnt2, int* __restrict__ rowptr,
                           int* __restrict__ bsums, int n) {
    __shared__ int sm[SCAN_B];
    int i = blockIdx.x * SCAN_B + threadIdx.x;
    int v = 0;
    if (i < n) {
        const int* c = &cnt2[i * NB];
        #pragma unroll
        for (int b = 0; b < NB; ++b) v += c[b];
    }
    sm[threadIdx.x] = v;
    __syncthreads();
    for (int off = 1; off < SCAN_B; off <<= 1) {
        int t = (threadIdx.x >= (unsigned)off) ? sm[threadIdx.x - off] : 0;
        __syncthreads();
        sm[threadIdx.x] += t;
        __syncthreads();
    }
    if (i < n) rowptr[i] = sm[threadIdx.x] - v;           // exclusive within block
    if (threadIdx.x == SCAN_B - 1) bsums[blockIdx.x] = sm[threadIdx.x];
}

__global__ void scan_pass2(int* __restrict__ bsums, int nb) {
    __shared__ int sm[512];
    int tid = threadIdx.x;
    int v = (tid < nb) ? bsums[tid] : 0;
    sm[tid] = v;
    __syncthreads();
    for (int off = 1; off < 512; off <<= 1) {
        int t = (tid >= off) ? sm[tid - off] : 0;
        __syncthreads();
        sm[tid] += t;
        __syncthreads();
    }
    if (tid < nb) bsums[tid] = sm[tid] - v;
}

__global__ void scan_pass3(int* __restrict__ rowptr, const int* __restrict__ bsums, int n) {
    int i = blockIdx.x * blockDim.x + threadIdx.x;
    if (i < n) rowptr[i] += bsums[i / SCAN_B];
}

// rowptr2[r*NB+b] = rowptr[r] + prefix of cnt2[r][0..b); also seeds cursor2.
__global__ void rowptr2_kernel(const int* __restrict__ rowptr, const int* __restrict__ cnt2,
                               int* __restrict__ rowptr2, int* __restrict__ cursor2,
                               int n, int e) {
    int r = blockIdx.x * blockDim.x + threadIdx.x;
    if (r < n) {
        int run = rowptr[r];
        const int* c = &cnt2[r * NB];
        #pragma unroll
        for (int b = 0; b < NB; ++b) {
            rowptr2[r * NB + b] = run;
            cursor2[r * NB + b] = run;
            run += c[b];
        }
    }
    if (r == 0) rowptr2[(size_t)n * NB] = e;
}

__global__ void scatter2_kernel(const int* __restrict__ rows, const int* __restrict__ cols,
                                const float* __restrict__ vals, int* __restrict__ cursor2,
                                unsigned* __restrict__ csr_pk, int e) {
    int i = blockIdx.x * blockDim.x + threadIdx.x;
    if (i < e) {
        int r = rows[i];
        int c = cols[i];
        int p = atomicAdd(&cursor2[r * NB + (c >> 12)], 1);
        int q = (int)rintf(vals[i] * 1048576.0f);   // val < 1/32 -> q <= 32768
        if (q > 32767) q = 32767;
        csr_pk[p] = ((unsigned)c << 15) | (unsigned)q;
    }
}

// ---------------------------------------------------------------------------
// helpers
// ---------------------------------------------------------------------------
__device__ inline float4 dec8(uint2 p) {
    __half2 h01 = *(__half2*)&p.x;
    __half2 h23 = *(__half2*)&p.y;
    float2 f01 = __half22float2(h01);
    float2 f23 = __half22float2(h23);
    return make_float4(f01.x, f01.y, f23.x, f23.y);
}

__device__ inline void gload16(const void* g, void* l) {
    __builtin_amdgcn_global_load_lds((const __attribute__((address_space(1))) void*)g,
                                     (__attribute__((address_space(3))) void*)l,
                                     16, 0, 0);
}

// ---------------------------------------------------------------------------
// Weight converters (tiny, once per launch)
// ---------------------------------------------------------------------------
__global__ void convert_win(const float* __restrict__ in, __half* __restrict__ out) {
    int idx = blockIdx.x * blockDim.x + threadIdx.x;
    if (idx < NFEAT * NH) {
        int k = idx >> 8;
        int n = idx & 255;
        out[n * NFEAT + k] = __float2half(in[idx]);
    }
}

__global__ void convert_convw(const float* __restrict__ in, __half* __restrict__ out) {
    int idx = blockIdx.x * blockDim.x + threadIdx.x;
    if (idx < NL * NH * NH) {
        int l = idx >> 16;
        int rem = idx & 65535;
        int k = rem >> 8;
        int n = rem & 255;
        out[(size_t)l * 65536 + n * 256 + k] = __float2half(in[idx]);
    }
}

__global__ void convert_wout(const float* __restrict__ in, __half* __restrict__ out) {
    int idx = blockIdx.x * blockDim.x + threadIdx.x;
    if (idx < 64 * 256) {
        int ncol = idx >> 8;     // 0..63
        int k    = idx & 255;    // 0..255
        out[idx] = (ncol < NC) ? __float2half(in[k * NC + ncol]) : __float2half(0.f);
    }
}

// ---------------------------------------------------------------------------
// Persistent bucket-sweep SpMM (half feature range per dispatch):
// 1024 blocks x 4 waves, all resident (launch_bounds 256,4 -> <=128 VGPR).
// Wave owns RPW consecutive rows; buckets swept in lockstep across the whole
// grid -> the active h16 col-band (~1-2MB + drift) stays L2-resident per XCD.
// Lane owns 2 feats (uint gather); fp32 accumulators held in registers.
// sup16 = fp16(0.9 * sum val*h16[col] + 0.1 * h016[r])
// ---------------------------------------------------------------------------
__global__ __launch_bounds__(256, 4) void spmm_pers(
    const int* __restrict__ rowptr2, const unsigned* __restrict__ csr_pk,
    const __half* __restrict__ h16, const __half* __restrict__ h016,
    __half* __restrict__ sup16, int n, int uoff)
{
    __shared__ int bnd[RPB * NB + 1];           // 2501 ints
    const int tid   = threadIdx.x;
    const int lane  = tid & 63;
    const int widx  = tid >> 6;
    const int r0blk = blockIdx.x * RPB;
    const int jmax  = n * NB;
    for (int j = tid; j <= RPB * NB; j += 256) {
        int g = r0blk * NB + j;
        bnd[j] = rowptr2[g > jmax ? jmax : g];
    }
    __syncthreads();

    const int fo = uoff + lane;                 // uint index within row (0..127)
    const unsigned* hv = (const unsigned*)h16;
    const int lr0 = widx * RPW;                 // local row base of this wave

    float2 acc[RPW];
    #pragma unroll
    for (int i = 0; i < RPW; ++i) acc[i] = make_float2(0.f, 0.f);

    for (int b = 0; b < NB; ++b) {
        #pragma unroll
        for (int i = 0; i < RPW; ++i) {
            int gr = r0blk + lr0 + i;
            if (gr >= n) continue;              // wave-uniform guard
            int e0 = bnd[(lr0 + i) * NB + b];
            int e1 = bnd[(lr0 + i) * NB + b + 1];
            for (int e = e0; e < e1; ++e) {
                unsigned a = csr_pk[e];
                float v = (float)(a & 32767u) * VAL_SCALE;
                unsigned pw = hv[(size_t)(a >> 15) * 128 + fo];
                float2 x = __half22float2(*(__half2*)&pw);
                acc[i].x += v * x.x;
                acc[i].y += v * x.y;
            }
        }
    }

    #pragma unroll
    for (int i = 0; i < RPW; ++i) {
        int gr = r0blk + lr0 + i;
        if (gr >= n) continue;
        unsigned s0w = ((const unsigned*)h016)[(size_t)gr * 128 + fo];
        float2 s0 = __half22float2(*(__half2*)&s0w);
        float2 o;
        o.x = 0.9f * acc[i].x + 0.1f * s0.x;
        o.y = 0.9f * acc[i].y + 0.1f * s0.y;
        __half2 hh = __floats2half2_rn(o.x, o.y);
        ((unsigned*)sup16)[(size_t)gr * 128 + fo] = *(unsigned*)&hh;
    }
}

// ---------------------------------------------------------------------------
// fp16 MFMA GEMM: out16[M,256] = epilogue(A[M,K] @ BT[256,K]^T)
//   mode 0: relu(acc + bias[n]);  mode 1: relu(theta*acc + (1-theta)*Csrc16)
// BM=128, BN=256, BK=32. 512 threads = 8 waves (2Mx4N), 64x64/wave.
// ---------------------------------------------------------------------------
template <bool AFLOAT>
__global__ __launch_bounds__(512) void mfma_gemm(
    const void* __restrict__ Aptr, const __half* __restrict__ BT,
    const float* __restrict__ bias, const __half* __restrict__ Csrc16,
    __half* __restrict__ out16, int M, int K,
    float theta, float omt, int mode)
{
    __shared__ __align__(16) char smem[49152];   // 2 bufs x (A 8KB + B 16KB)
    const int tid  = threadIdx.x;
    const int lane = tid & 63;
    const int w    = tid >> 6;        // 0..7
    const int wr   = w >> 2;          // 0..1  (M half)
    const int wc   = w & 3;           // 0..3  (N quarter)
    const int bm0  = blockIdx.x * 128;
    const size_t strideB = (size_t)K * 2;

    f32x4 acc[4][4];
    #pragma unroll
    for (int m = 0; m < 4; ++m)
        #pragma unroll
        for (int n = 0; n < 4; ++n)
            acc[m][n] = (f32x4)0.f;

    auto stage = [&](int kt, int buf) {
        char* base = smem + buf * 24576;
        const long k0b = (long)kt * 64;
        if constexpr (AFLOAT) {
            const float* A32 = (const float*)Aptr;
            #pragma unroll
            for (int it = 0; it < 2; ++it) {
                int idx = tid + it * 512;            // 0..1023
                int r   = idx >> 3;                  // 0..127
                int t   = idx & 7;                   // float4 slot
                int grow = bm0 + r; if (grow >= M) grow = M - 1;
                float4 f = *(const float4*)&A32[(size_t)grow * K + kt * 32 + t * 4];
                __half2 a = __floats2half2_rn(f.x, f.y);
                __half2 b = __floats2half2_rn(f.z, f.w);
                uint2 pk;
                pk.x = *(unsigned*)&a;
                pk.y = *(unsigned*)&b;
                int slot = t >> 1;
                int off  = r * 64 + ((slot ^ ((r >> 1) & 3)) << 4) + (t & 1) * 8;
                *(uint2*)(base + off) = pk;
            }
        } else {
            const char* A16 = (const char*)Aptr;
            int row = w * 16 + (lane >> 2);          // 8 chunks x 16 rows
            int q   = (lane & 3) * 16;
            int qs  = q ^ (((row >> 1) & 3) << 4);
            int grow = bm0 + row; if (grow >= M) grow = M - 1;
            gload16(A16 + (size_t)grow * strideB + k0b + qs, base + w * 1024);
        }
        #pragma unroll
        for (int i = 0; i < 2; ++i) {
            int ia  = w * 2 + i;
            int row = ia * 16 + (lane >> 2);         // 0..255, always valid
            int q   = (lane & 3) * 16;
            int qs  = q ^ (((row >> 1) & 3) << 4);
            gload16((const char*)BT + (size_t)row * strideB + k0b + qs,
                    base + 8192 + ia * 1024);
        }
    };

    auto compute = [&](int buf) {
        const char* As = smem + buf * 24576;
        const char* Bs = As + 8192;
        const int q = (lane >> 4) * 16;
        f16x8 af[4], bf[4];
        #pragma unroll
        for (int m = 0; m < 4; ++m) {
            int row = wr * 64 + m * 16 + (lane & 15);
            af[m] = *(const f16x8*)(As + row * 64 + (q ^ (((row >> 1) & 3) << 4)));
        }
        #pragma unroll
        for (int n = 0; n < 4; ++n) {
            int col = wc * 64 + n * 16 + (lane & 15);
            bf[n] = *(const f16x8*)(Bs + col * 64 + (q ^ (((col >> 1) & 3) << 4)));
        }
        #pragma unroll
        for (int m = 0; m < 4; ++m)
            #pragma unroll
            for (int n = 0; n < 4; ++n)
                acc[m][n] = __builtin_amdgcn_mfma_f32_16x16x32_f16(af[m], bf[n], acc[m][n], 0, 0, 0);
    };

    const int nkt = K >> 5;
    stage(0, 0);
    __syncthreads();
    for (int kt = 0; kt < nkt; ++kt) {
        if (kt + 1 < nkt) stage(kt + 1, (kt + 1) & 1);
        compute(kt & 1);
        __syncthreads();
    }

    #pragma unroll
    for (int m = 0; m < 4; ++m) {
        int rbase = bm0 + wr * 64 + m * 16 + (lane >> 4) * 4;
        #pragma unroll
        for (int r = 0; r < 4; ++r) {
            int grow = rbase + r;
            if (grow >= M) continue;
            #pragma unroll
            for (int n = 0; n < 4; ++n) {
                int gcol = wc * 64 + n * 16 + (lane & 15);
                float x = acc[m][n][r];
                if (mode == 0) {
                    x = fmaxf(x + bias[gcol], 0.f);
                } else {
                    float s = __half2float(Csrc16[(size_t)grow * 256 + gcol]);
                    x = fmaxf(theta * x + omt * s, 0.f);
                }
                out16[(size_t)grow * 256 + gcol] = __float2half(x);
            }
        }
    }
}

// ---------------------------------------------------------------------------
// Output MFMA GEMM: out32[M,40] = A16[M,256] @ WtOut16[64,256]^T + b_out
// ---------------------------------------------------------------------------
__global__ __launch_bounds__(256) void mfma_out(
    const __half* __restrict__ A16, const __half* __restrict__ BT,
    const float* __restrict__ bias, float* __restrict__ out32, int M)
{
    __shared__ __align__(16) char smem[40960];   // 2 bufs x (A 16KB + B 4KB)
    const int tid  = threadIdx.x;
    const int lane = tid & 63;
    const int w    = tid >> 6;        // 0..3 (M position)
    const int bm0  = blockIdx.x * 256;

    f32x4 acc[4][4];
    #pragma unroll
    for (int m = 0; m < 4; ++m)
        #pragma unroll
        for (int n = 0; n < 4; ++n)
            acc[m][n] = (f32x4)0.f;

    auto stage = [&](int kt, int buf) {
        char* base = smem + buf * 20480;
        const long k0b = (long)kt * 64;
        #pragma unroll
        for (int i = 0; i < 4; ++i) {
            int ia  = w * 4 + i;
            int row = ia * 16 + (lane >> 2);      // 0..255
            int q   = (lane & 3) * 16;
            int qs  = q ^ (((row >> 1) & 3) << 4);
            int grow = bm0 + row; if (grow >= M) grow = M - 1;
            gload16((const char*)A16 + (size_t)grow * 512 + k0b + qs, base + ia * 1024);
        }
        {
            int row = w * 16 + (lane >> 2);       // 0..63
            int q   = (lane & 3) * 16;
            int qs  = q ^ (((row >> 1) & 3) << 4);
            gload16((const char*)BT + (size_t)row * 512 + k0b + qs,
                    base + 16384 + w * 1024);
        }
    };

    auto compute = [&](int buf) {
        const char* As = smem + buf * 20480;
        const char* Bs = As + 16384;
        const int q = (lane >> 4) * 16;
        f16x8 af[4], bf[4];
        #pragma unroll
        for (int m = 0; m < 4; ++m) {
            int row = w * 64 + m * 16 + (lane & 15);
            af[m] = *(const f16x8*)(As + row * 64 + (q ^ (((row >> 1) & 3) << 4)));
        }
        #pragma unroll
        for (int n = 0; n < 4; ++n) {
            int col = n * 16 + (lane & 15);
            bf[n] = *(const f16x8*)(Bs + col * 64 + (q ^ (((col >> 1) & 3) << 4)));
        }
        #pragma unroll
        for (int m = 0; m < 4; ++m)
            #pragma unroll
            for (int n = 0; n < 4; ++n)
                acc[m][n] = __builtin_amdgcn_mfma_f32_16x16x32_f16(af[m], bf[n], acc[m][n], 0, 0, 0);
    };

    stage(0, 0);
    __syncthreads();
    for (int kt = 0; kt < 8; ++kt) {
        if (kt + 1 < 8) stage(kt + 1, (kt + 1) & 1);
        compute(kt & 1);
        __syncthreads();
    }

    #pragma unroll
    for (int m = 0; m < 4; ++m) {
        int rbase = bm0 + w * 64 + m * 16 + (lane >> 4) * 4;
        #pragma unroll
        for (int r = 0; r < 4; ++r) {
            int grow = rbase + r;
            if (grow >= M) continue;
            #pragma unroll
            for (int n = 0; n < 3; ++n) {
                int gcol = n * 16 + (lane & 15);
                if (gcol < NC)
                    out32[(size_t)grow * NC + gcol] = acc[m][n][r] + bias[gcol];
            }
        }
    }
}

// ---------------------------------------------------------------------------
// Host-side launch
// ---------------------------------------------------------------------------
extern "C" void kernel_launch(void* const* d_in, const int* in_sizes, int n_in,
                              void* d_out, int out_size, void* d_ws, size_t ws_size,
                              hipStream_t stream) {
    const float* features = (const float*)d_in[0];
    const int*   erows    = (const int*)d_in[1];
    const int*   ecols    = (const int*)d_in[2];
    const float* evals    = (const float*)d_in[3];
    const float* W_in     = (const float*)d_in[4];
    const float* b_in     = (const float*)d_in[5];
    const float* convW    = (const float*)d_in[6];
    const float* W_out    = (const float*)d_in[7];
    const float* b_out    = (const float*)d_in[8];
    float* out = (float*)d_out;

    const int n = NNODE;
    const int e = NEDGE;

    char* w = (char*)d_ws;
    auto alloc = [&](size_t bytes) -> void* {
        void* p = (void*)w;
        w += (bytes + 255) & ~(size_t)255;
        return p;
    };
    __half*   h0_16    = (__half*)alloc((size_t)n * NH * 2);
    __half*   hb_16    = (__half*)alloc((size_t)n * NH * 2);
    __half*   sup16    = (__half*)alloc((size_t)n * NH * 2);
    __half*   WtIn16   = (__half*)alloc((size_t)NFEAT * NH * 2);
    __half*   convWt16 = (__half*)alloc((size_t)NL * NH * NH * 2);
    __half*   WtOut16  = (__half*)alloc((size_t)64 * NH * 2);
    int*      rowptr   = (int*)alloc((size_t)(n + 1) * 4);
    int*      bsums    = (int*)alloc(4096 * 4);
    int*      cnt2     = (int*)alloc((size_t)n * NB * 4);
    int*      rowptr2  = (int*)alloc(((size_t)n * NB + 1) * 4);
    int*      cursor2  = (int*)alloc((size_t)n * NB * 4);
    unsigned* csr_pk   = (unsigned*)alloc((size_t)e * 4);

    // --- Weight converters ---
    convert_win<<<(NFEAT * NH + 255) / 256, 256, 0, stream>>>(W_in, WtIn16);
    convert_convw<<<(NL * NH * NH + 255) / 256, 256, 0, stream>>>(convW, convWt16);
    convert_wout<<<(64 * 256 + 255) / 256, 256, 0, stream>>>(W_out, WtOut16);

    // --- CSR2 build: (row, col-bucket) segmented edge list ---
    hipMemsetAsync(cnt2, 0, (size_t)n * NB * 4, stream);
    cnt2_kernel<<<(e + 255) / 256, 256, 0, stream>>>(erows, ecols, cnt2, e);
    int nb = (n + SCAN_B - 1) / SCAN_B;
    scan_pass1<<<nb, SCAN_B, 0, stream>>>(cnt2, rowptr, bsums, n);
    scan_pass2<<<1, 512, 0, stream>>>(bsums, nb);
    scan_pass3<<<nb, SCAN_B, 0, stream>>>(rowptr, bsums, n);
    rowptr2_kernel<<<(n + 255) / 256, 256, 0, stream>>>(rowptr, cnt2, rowptr2, cursor2, n, e);
    scatter2_kernel<<<(e + 255) / 256, 256, 0, stream>>>(erows, ecols, evals, cursor2,
                                                         csr_pk, e);

    // --- h0_16 = fp16(relu(features @ W_in + b_in)) ---
    dim3 gmm((n + 127) / 128, 1);
    mfma_gemm<true><<<gmm, 512, 0, stream>>>(features, WtIn16, b_in, nullptr,
                                             h0_16, n, NFEAT, 0.f, 0.f, 0);

    // --- 8 GCNII layers: persistent bucket-sweep SpMM (2 feature halves) ---
    const __half* hcur16 = h0_16;
    for (int i = 0; i < NL; ++i) {
        spmm_pers<<<PBLK, 256, 0, stream>>>(rowptr2, csr_pk, hcur16, h0_16, sup16, n, 0);
        spmm_pers<<<PBLK, 256, 0, stream>>>(rowptr2, csr_pk, hcur16, h0_16, sup16, n, 64);
        double th = log(0.5 / (double)(i + 1) + 1.0);
        mfma_gemm<false><<<gmm, 512, 0, stream>>>(sup16, convWt16 + (size_t)i * NH * NH,
                                                  nullptr, sup16, hb_16,
                                                  n, NH, (float)th, (float)(1.0 - th), 1);
        hcur16 = hb_16;
    }

    // --- out = h @ W_out + b_out (MFMA, padded to 64 cols) ---
    mfma_out<<<(n + 255) / 256, 256, 0, stream>>>(hb_16, WtOut16, b_out, out, n);
}

// Round 9
// 2827.628 us; speedup vs baseline: 3.0616x; 3.0616x over previous
//
#include <hip/hip_runtime.h>
#include <hip/hip_fp16.h>
#include <math.h>

// Problem constants (fixed by the reference)
#define NNODE   100000
#define NEDGE   3200000
#define NFEAT   512
#define NH      256
#define NC      40
#define NL      8

#define SCAN_B  256
#define NB      25        // col buckets: b = col >> 12 (edges within a row sorted by bucket)

typedef _Float16 f16x8 __attribute__((ext_vector_type(8)));
typedef float    f32x4 __attribute__((ext_vector_type(4)));

#define VAL_SCALE 9.5367431640625e-7f   // 2^-20

// ---------------------------------------------------------------------------
// CSR2 build: per-(row,bucket) count -> row scan -> per-row prefix -> scatter
// Result: csr_pk edges grouped by row, bucket-sorted (ascending col) in-row.
// ---------------------------------------------------------------------------
__global__ void cnt2_kernel(const int* __restrict__ rows, const int* __restrict__ cols,
                            int* __restrict__ cnt2, int e) {
    int i = blockIdx.x * blockDim.x + threadIdx.x;
    if (i < e) atomicAdd(&cnt2[rows[i] * NB + (cols[i] >> 12)], 1);
}

// scan pass 1: per-row degree = sum of its NB bucket counts, block-local scan
__global__ void scan_pass1(const int* __restrict__ cnt2, int* __restrict__ rowptr,
                           int* __restrict__ bsums, int n) {
    __shared__ int sm[SCAN_B];
    int i = blockIdx.x * SCAN_B + threadIdx.x;
    int v = 0;
    if (i < n) {
        const int* c = &cnt2[i * NB];
        #pragma unroll
        for (int b = 0; b < NB; ++b) v += c[b];
    }
    sm[threadIdx.x] = v;
    __syncthreads();
    for (int off = 1; off < SCAN_B; off <<= 1) {
        int t = (threadIdx.x >= (unsigned)off) ? sm[threadIdx.x - off] : 0;
        __syncthreads();
        sm[threadIdx.x] += t;
        __syncthreads();
    }
    if (i < n) rowptr[i] = sm[threadIdx.x] - v;           // exclusive within block
    if (threadIdx.x == SCAN_B - 1) bsums[blockIdx.x] = sm[threadIdx.x];
}

__global__ void scan_pass2(int* __restrict__ bsums, int nb) {
    __shared__ int sm[512];
    int tid = threadIdx.x;
    int v = (tid < nb) ? bsums[tid] : 0;
    sm[tid] = v;
    __syncthreads();
    for (int off = 1; off < 512; off <<= 1) {
        int t = (tid >= off) ? sm[tid - off] : 0;
        __syncthreads();
        sm[tid] += t;
        __syncthreads();
    }
    if (tid < nb) bsums[tid] = sm[tid] - v;
}

__global__ void scan_pass3(int* __restrict__ rowptr, const int* __restrict__ bsums,
                           int n, int total) {
    int i = blockIdx.x * blockDim.x + threadIdx.x;
    if (i < n) rowptr[i] += bsums[i / SCAN_B];
    if (i == 0) rowptr[n] = total;
}

// cursor2[r*NB+b] = rowptr[r] + prefix of cnt2[r][0..b)
__global__ void rowptr2_kernel(const int* __restrict__ rowptr, const int* __restrict__ cnt2,
                               int* __restrict__ cursor2, int n) {
    int r = blockIdx.x * blockDim.x + threadIdx.x;
    if (r < n) {
        int run = rowptr[r];
        const int* c = &cnt2[r * NB];
        #pragma unroll
        for (int b = 0; b < NB; ++b) {
            cursor2[r * NB + b] = run;
            run += c[b];
        }
    }
}

__global__ void scatter2_kernel(const int* __restrict__ rows, const int* __restrict__ cols,
                                const float* __restrict__ vals, int* __restrict__ cursor2,
                                unsigned* __restrict__ csr_pk, int e) {
    int i = blockIdx.x * blockDim.x + threadIdx.x;
    if (i < e) {
        int r = rows[i];
        int c = cols[i];
        int p = atomicAdd(&cursor2[r * NB + (c >> 12)], 1);
        int q = (int)rintf(vals[i] * 1048576.0f);   // val < 1/32 -> q <= 32768
        if (q > 32767) q = 32767;
        csr_pk[p] = ((unsigned)c << 15) | (unsigned)q;
    }
}

// ---------------------------------------------------------------------------
// helpers
// ---------------------------------------------------------------------------
__device__ inline float4 dec8(uint2 p) {
    __half2 h01 = *(__half2*)&p.x;
    __half2 h23 = *(__half2*)&p.y;
    float2 f01 = __half22float2(h01);
    float2 f23 = __half22float2(h23);
    return make_float4(f01.x, f01.y, f23.x, f23.y);
}

__device__ inline void gload16(const void* g, void* l) {
    __builtin_amdgcn_global_load_lds((const __attribute__((address_space(1))) void*)g,
                                     (__attribute__((address_space(3))) void*)l,
                                     16, 0, 0);
}

// ---------------------------------------------------------------------------
// Weight converters (tiny, once per launch)
// ---------------------------------------------------------------------------
__global__ void convert_win(const float* __restrict__ in, __half* __restrict__ out) {
    int idx = blockIdx.x * blockDim.x + threadIdx.x;
    if (idx < NFEAT * NH) {
        int k = idx >> 8;
        int n = idx & 255;
        out[n * NFEAT + k] = __float2half(in[idx]);
    }
}

__global__ void convert_convw(const float* __restrict__ in, __half* __restrict__ out) {
    int idx = blockIdx.x * blockDim.x + threadIdx.x;
    if (idx < NL * NH * NH) {
        int l = idx >> 16;
        int rem = idx & 65535;
        int k = rem >> 8;
        int n = rem & 255;
        out[(size_t)l * 65536 + n * 256 + k] = __float2half(in[idx]);
    }
}

__global__ void convert_wout(const float* __restrict__ in, __half* __restrict__ out) {
    int idx = blockIdx.x * blockDim.x + threadIdx.x;
    if (idx < 64 * 256) {
        int ncol = idx >> 8;     // 0..63
        int k    = idx & 255;    // 0..255
        out[idx] = (ncol < NC) ? __float2half(in[k * NC + ncol]) : __float2half(0.f);
    }
}

// ---------------------------------------------------------------------------
// SpMM, sorted-sweep: one wave per row, edges ascending-col (bucket-sorted),
// 8-deep gather unroll for MLP. Lane owns 4 feats (8B uint2 gather, coalesced:
// 64 lanes cover the full 512B h-row). fp32 accumulate.
// sup16 = fp16(0.9 * sum val*h16[col] + 0.1 * h016[r])
// Concurrent waves all sweep col-space 0->100k at the same rate -> the hot
// h16 col-band stays cache-resident (round-7 evidence: lockstep FETCH 178MB).
// ---------------------------------------------------------------------------
__global__ __launch_bounds__(256) void spmm_sorted(
    const int* __restrict__ rowptr, const unsigned* __restrict__ csr_pk,
    const __half* __restrict__ h16, const __half* __restrict__ h016,
    __half* __restrict__ sup16, int n)
{
    int lane = threadIdx.x & 63;
    int r = blockIdx.x * 4 + (threadIdx.x >> 6);
    if (r >= n) return;
    int e0 = rowptr[r], e1 = rowptr[r + 1];
    const uint2* hv = (const uint2*)h16;
    float4 acc = make_float4(0.f, 0.f, 0.f, 0.f);
    int e = e0;
    #pragma unroll 1
    for (; e + 8 <= e1; e += 8) {
        unsigned a[8];
        uint2 p[8];
        #pragma unroll
        for (int j = 0; j < 8; ++j) a[j] = csr_pk[e + j];
        #pragma unroll
        for (int j = 0; j < 8; ++j) p[j] = hv[(size_t)(a[j] >> 15) * 64 + lane];
        #pragma unroll
        for (int j = 0; j < 8; ++j) {
            float v = (float)(a[j] & 32767u) * VAL_SCALE;
            float4 x = dec8(p[j]);
            acc.x += v * x.x; acc.y += v * x.y;
            acc.z += v * x.z; acc.w += v * x.w;
        }
    }
    #pragma unroll 1
    for (; e < e1; ++e) {
        unsigned a = csr_pk[e];
        float v = (float)(a & 32767u) * VAL_SCALE;
        float4 x = dec8(hv[(size_t)(a >> 15) * 64 + lane]);
        acc.x += v * x.x; acc.y += v * x.y; acc.z += v * x.z; acc.w += v * x.w;
    }
    float4 s0 = dec8(((const uint2*)h016)[(size_t)r * 64 + lane]);
    float4 o;
    o.x = 0.9f * acc.x + 0.1f * s0.x;
    o.y = 0.9f * acc.y + 0.1f * s0.y;
    o.z = 0.9f * acc.z + 0.1f * s0.z;
    o.w = 0.9f * acc.w + 0.1f * s0.w;
    __half2 ha = __floats2half2_rn(o.x, o.y);
    __half2 hb = __floats2half2_rn(o.z, o.w);
    uint2 pk;
    pk.x = *(unsigned*)&ha;
    pk.y = *(unsigned*)&hb;
    ((uint2*)sup16)[(size_t)r * 64 + lane] = pk;
}

// ---------------------------------------------------------------------------
// fp16 MFMA GEMM: out16[M,256] = epilogue(A[M,K] @ BT[256,K]^T)
//   mode 0: relu(acc + bias[n]);  mode 1: relu(theta*acc + (1-theta)*Csrc16)
// BM=128, BN=256, BK=32. 512 threads = 8 waves (2Mx4N), 64x64/wave.
// ---------------------------------------------------------------------------
template <bool AFLOAT>
__global__ __launch_bounds__(512) void mfma_gemm(
    const void* __restrict__ Aptr, const __half* __restrict__ BT,
    const float* __restrict__ bias, const __half* __restrict__ Csrc16,
    __half* __restrict__ out16, int M, int K,
    float theta, float omt, int mode)
{
    __shared__ __align__(16) char smem[49152];   // 2 bufs x (A 8KB + B 16KB)
    const int tid  = threadIdx.x;
    const int lane = tid & 63;
    const int w    = tid >> 6;        // 0..7
    const int wr   = w >> 2;          // 0..1  (M half)
    const int wc   = w & 3;           // 0..3  (N quarter)
    const int bm0  = blockIdx.x * 128;
    const size_t strideB = (size_t)K * 2;

    f32x4 acc[4][4];
    #pragma unroll
    for (int m = 0; m < 4; ++m)
        #pragma unroll
        for (int n = 0; n < 4; ++n)
            acc[m][n] = (f32x4)0.f;

    auto stage = [&](int kt, int buf) {
        char* base = smem + buf * 24576;
        const long k0b = (long)kt * 64;
        if constexpr (AFLOAT) {
            const float* A32 = (const float*)Aptr;
            #pragma unroll
            for (int it = 0; it < 2; ++it) {
                int idx = tid + it * 512;            // 0..1023
                int r   = idx >> 3;                  // 0..127
                int t   = idx & 7;                   // float4 slot
                int grow = bm0 + r; if (grow >= M) grow = M - 1;
                float4 f = *(const float4*)&A32[(size_t)grow * K + kt * 32 + t * 4];
                __half2 a = __floats2half2_rn(f.x, f.y);
                __half2 b = __floats2half2_rn(f.z, f.w);
                uint2 pk;
                pk.x = *(unsigned*)&a;
                pk.y = *(unsigned*)&b;
                int slot = t >> 1;
                int off  = r * 64 + ((slot ^ ((r >> 1) & 3)) << 4) + (t & 1) * 8;
                *(uint2*)(base + off) = pk;
            }
        } else {
            const char* A16 = (const char*)Aptr;
            int row = w * 16 + (lane >> 2);          // 8 chunks x 16 rows
            int q   = (lane & 3) * 16;
            int qs  = q ^ (((row >> 1) & 3) << 4);
            int grow = bm0 + row; if (grow >= M) grow = M - 1;
            gload16(A16 + (size_t)grow * strideB + k0b + qs, base + w * 1024);
        }
        #pragma unroll
        for (int i = 0; i < 2; ++i) {
            int ia  = w * 2 + i;
            int row = ia * 16 + (lane >> 2);         // 0..255, always valid
            int q   = (lane & 3) * 16;
            int qs  = q ^ (((row >> 1) & 3) << 4);
            gload16((const char*)BT + (size_t)row * strideB + k0b + qs,
                    base + 8192 + ia * 1024);
        }
    };

    auto compute = [&](int buf) {
        const char* As = smem + buf * 24576;
        const char* Bs = As + 8192;
        const int q = (lane >> 4) * 16;
        f16x8 af[4], bf[4];
        #pragma unroll
        for (int m = 0; m < 4; ++m) {
            int row = wr * 64 + m * 16 + (lane & 15);
            af[m] = *(const f16x8*)(As + row * 64 + (q ^ (((row >> 1) & 3) << 4)));
        }
        #pragma unroll
        for (int n = 0; n < 4; ++n) {
            int col = wc * 64 + n * 16 + (lane & 15);
            bf[n] = *(const f16x8*)(Bs + col * 64 + (q ^ (((col >> 1) & 3) << 4)));
        }
        #pragma unroll
        for (int m = 0; m < 4; ++m)
            #pragma unroll
            for (int n = 0; n < 4; ++n)
                acc[m][n] = __builtin_amdgcn_mfma_f32_16x16x32_f16(af[m], bf[n], acc[m][n], 0, 0, 0);
    };

    const int nkt = K >> 5;
    stage(0, 0);
    __syncthreads();
    for (int kt = 0; kt < nkt; ++kt) {
        if (kt + 1 < nkt) stage(kt + 1, (kt + 1) & 1);
        compute(kt & 1);
        __syncthreads();
    }

    #pragma unroll
    for (int m = 0; m < 4; ++m) {
        int rbase = bm0 + wr * 64 + m * 16 + (lane >> 4) * 4;
        #pragma unroll
        for (int r = 0; r < 4; ++r) {
            int grow = rbase + r;
            if (grow >= M) continue;
            #pragma unroll
            for (int n = 0; n < 4; ++n) {
                int gcol = wc * 64 + n * 16 + (lane & 15);
                float x = acc[m][n][r];
                if (mode == 0) {
                    x = fmaxf(x + bias[gcol], 0.f);
                } else {
                    float s = __half2float(Csrc16[(size_t)grow * 256 + gcol]);
                    x = fmaxf(theta * x + omt * s, 0.f);
                }
                out16[(size_t)grow * 256 + gcol] = __float2half(x);
            }
        }
    }
}

// ---------------------------------------------------------------------------
// Output MFMA GEMM: out32[M,40] = A16[M,256] @ WtOut16[64,256]^T + b_out
// ---------------------------------------------------------------------------
__global__ __launch_bounds__(256) void mfma_out(
    const __half* __restrict__ A16, const __half* __restrict__ BT,
    const float* __restrict__ bias, float* __restrict__ out32, int M)
{
    __shared__ __align__(16) char smem[40960];   // 2 bufs x (A 16KB + B 4KB)
    const int tid  = threadIdx.x;
    const int lane = tid & 63;
    const int w    = tid >> 6;        // 0..3 (M position)
    const int bm0  = blockIdx.x * 256;

    f32x4 acc[4][4];
    #pragma unroll
    for (int m = 0; m < 4; ++m)
        #pragma unroll
        for (int n = 0; n < 4; ++n)
            acc[m][n] = (f32x4)0.f;

    auto stage = [&](int kt, int buf) {
        char* base = smem + buf * 20480;
        const long k0b = (long)kt * 64;
        #pragma unroll
        for (int i = 0; i < 4; ++i) {
            int ia  = w * 4 + i;
            int row = ia * 16 + (lane >> 2);      // 0..255
            int q   = (lane & 3) * 16;
            int qs  = q ^ (((row >> 1) & 3) << 4);
            int grow = bm0 + row; if (grow >= M) grow = M - 1;
            gload16((const char*)A16 + (size_t)grow * 512 + k0b + qs, base + ia * 1024);
        }
        {
            int row = w * 16 + (lane >> 2);       // 0..63
            int q   = (lane & 3) * 16;
            int qs  = q ^ (((row >> 1) & 3) << 4);
            gload16((const char*)BT + (size_t)row * 512 + k0b + qs,
                    base + 16384 + w * 1024);
        }
    };

    auto compute = [&](int buf) {
        const char* As = smem + buf * 20480;
        const char* Bs = As + 16384;
        const int q = (lane >> 4) * 16;
        f16x8 af[4], bf[4];
        #pragma unroll
        for (int m = 0; m < 4; ++m) {
            int row = w * 64 + m * 16 + (lane & 15);
            af[m] = *(const f16x8*)(As + row * 64 + (q ^ (((row >> 1) & 3) << 4)));
        }
        #pragma unroll
        for (int n = 0; n < 4; ++n) {
            int col = n * 16 + (lane & 15);
            bf[n] = *(const f16x8*)(Bs + col * 64 + (q ^ (((col >> 1) & 3) << 4)));
        }
        #pragma unroll
        for (int m = 0; m < 4; ++m)
            #pragma unroll
            for (int n = 0; n < 4; ++n)
                acc[m][n] = __builtin_amdgcn_mfma_f32_16x16x32_f16(af[m], bf[n], acc[m][n], 0, 0, 0);
    };

    stage(0, 0);
    __syncthreads();
    for (int kt = 0; kt < 8; ++kt) {
        if (kt + 1 < 8) stage(kt + 1, (kt + 1) & 1);
        compute(kt & 1);
        __syncthreads();
    }

    #pragma unroll
    for (int m = 0; m < 4; ++m) {
        int rbase = bm0 + w * 64 + m * 16 + (lane >> 4) * 4;
        #pragma unroll
        for (int r = 0; r < 4; ++r) {
            int grow = rbase + r;
            if (grow >= M) continue;
            #pragma unroll
            for (int n = 0; n < 3; ++n) {
                int gcol = n * 16 + (lane & 15);
                if (gcol < NC)
                    out32[(size_t)grow * NC + gcol] = acc[m][n][r] + bias[gcol];
            }
        }
    }
}

// ---------------------------------------------------------------------------
// Host-side launch
// ---------------------------------------------------------------------------
extern "C" void kernel_launch(void* const* d_in, const int* in_sizes, int n_in,
                              void* d_out, int out_size, void* d_ws, size_t ws_size,
                              hipStream_t stream) {
    const float* features = (const float*)d_in[0];
    const int*   erows    = (const int*)d_in[1];
    const int*   ecols    = (const int*)d_in[2];
    const float* evals    = (const float*)d_in[3];
    const float* W_in     = (const float*)d_in[4];
    const float* b_in     = (const float*)d_in[5];
    const float* convW    = (const float*)d_in[6];
    const float* W_out    = (const float*)d_in[7];
    const float* b_out    = (const float*)d_in[8];
    float* out = (float*)d_out;

    const int n = NNODE;
    const int e = NEDGE;

    char* w = (char*)d_ws;
    auto alloc = [&](size_t bytes) -> void* {
        void* p = (void*)w;
        w += (bytes + 255) & ~(size_t)255;
        return p;
    };
    __half*   h0_16    = (__half*)alloc((size_t)n * NH * 2);
    __half*   hb_16    = (__half*)alloc((size_t)n * NH * 2);
    __half*   sup16    = (__half*)alloc((size_t)n * NH * 2);
    __half*   WtIn16   = (__half*)alloc((size_t)NFEAT * NH * 2);
    __half*   convWt16 = (__half*)alloc((size_t)NL * NH * NH * 2);
    __half*   WtOut16  = (__half*)alloc((size_t)64 * NH * 2);
    int*      rowptr   = (int*)alloc((size_t)(n + 1) * 4);
    int*      bsums    = (int*)alloc(4096 * 4);
    int*      cnt2     = (int*)alloc((size_t)n * NB * 4);
    int*      cursor2  = (int*)alloc((size_t)n * NB * 4);
    unsigned* csr_pk   = (unsigned*)alloc((size_t)e * 4);

    // --- Weight converters ---
    convert_win<<<(NFEAT * NH + 255) / 256, 256, 0, stream>>>(W_in, WtIn16);
    convert_convw<<<(NL * NH * NH + 255) / 256, 256, 0, stream>>>(convW, convWt16);
    convert_wout<<<(64 * 256 + 255) / 256, 256, 0, stream>>>(W_out, WtOut16);

    // --- CSR2 build: per-row edges, bucket-sorted (ascending col) in-row ---
    hipMemsetAsync(cnt2, 0, (size_t)n * NB * 4, stream);
    cnt2_kernel<<<(e + 255) / 256, 256, 0, stream>>>(erows, ecols, cnt2, e);
    int nb = (n + SCAN_B - 1) / SCAN_B;
    scan_pass1<<<nb, SCAN_B, 0, stream>>>(cnt2, rowptr, bsums, n);
    scan_pass2<<<1, 512, 0, stream>>>(bsums, nb);
    scan_pass3<<<nb, SCAN_B, 0, stream>>>(rowptr, bsums, n, e);
    rowptr2_kernel<<<(n + 255) / 256, 256, 0, stream>>>(rowptr, cnt2, cursor2, n);
    scatter2_kernel<<<(e + 255) / 256, 256, 0, stream>>>(erows, ecols, evals, cursor2,
                                                         csr_pk, e);

    // --- h0_16 = fp16(relu(features @ W_in + b_in)) ---
    dim3 gmm((n + 127) / 128, 1);
    mfma_gemm<true><<<gmm, 512, 0, stream>>>(features, WtIn16, b_in, nullptr,
                                             h0_16, n, NFEAT, 0.f, 0.f, 0);

    // --- 8 GCNII layers: sorted-sweep SpMM (full row, unroll-8 MLP) ---
    const __half* hcur16 = h0_16;
    for (int i = 0; i < NL; ++i) {
        spmm_sorted<<<(n + 3) / 4, 256, 0, stream>>>(rowptr, csr_pk,
                                                     hcur16, h0_16, sup16, n);
        double th = log(0.5 / (double)(i + 1) + 1.0);
        mfma_gemm<false><<<gmm, 512, 0, stream>>>(sup16, convWt16 + (size_t)i * NH * NH,
                                                  nullptr, sup16, hb_16,
                                                  n, NH, (float)th, (float)(1.0 - th), 1);
        hcur16 = hb_16;
    }

    // --- out = h @ W_out + b_out (MFMA, padded to 64 cols) ---
    mfma_out<<<(n + 255) / 256, 256, 0, stream>>>(hb_16, WtOut16, b_out, out, n);
}